// Round 7
// baseline (157.487 us; speedup 1.0000x reference)
//
#include <hip/hip_runtime.h>

#define NPG 100     // nodes per graph
#define HF 64       // hidden width
#define ST 72       // Trm row stride (bf16): 64 + 8 pad (odd 16B units -> conflict-free b128)
#define SAT 136     // Tc row stride (bf16): 128 + 8 pad (odd 16B units -> conflict-free b128)
#define CMW 29      // count-matrix words per row (ODD -> conflict-free strided column reads)

typedef float  f4   __attribute__((ext_vector_type(4)));
typedef float  f16v __attribute__((ext_vector_type(16)));
typedef short  bf8  __attribute__((ext_vector_type(8)));

#define SZ_TC   (HF * SAT * 2)            // 17408 per Tc buffer
#define SZ_TRM  (128 * ST * 2)            // 18432 per Trm buffer
#define OFF_TC1  SZ_TC                    // Tc parity-1 @ 17408 (Cm overlays first 14848 B)
#define OFF_TRM0 (2 * SZ_TC)              // 34816
#define OFF_MISC (OFF_TRM0 + 2 * SZ_TRM)  // 71680
#define SMEM_BYTES (OFF_MISC + 1280)      // 72960 -> 2 blocks/CU
#define CMBYTES (128 * CMW * 4)           // 14848 <= SZ_TC
// misc: deg[112] u32 @0 (448) | pool[64] @448 | gvn[64] @704 | zf[32] @960
//       | logits[10] @1088 | lsep @1152

// bf16 weight workspace (d_ws), layout Wt[k5][fo][fi]:
//   W1t [5][64][16] @ 0 (fi zero-padded 3->16) | W2t [5][64][64] @ 5120 | W3t @ 25600
#define WT_TOTAL 46080

__device__ __forceinline__ unsigned short f2bf(float f) {
    unsigned u = __float_as_uint(f);
    u += 0x7fffu + ((u >> 16) & 1u);   // round-to-nearest-even
    return (unsigned short)(u >> 16);
}
// HW packed f32->bf16 (RNE), lo -> bits[15:0], hi -> bits[31:16].
__device__ __forceinline__ unsigned cvt_pk_bf16(float lo, float hi) {
    unsigned r;
    asm("v_cvt_pk_bf16_f32 %0, %1, %2" : "=v"(r) : "v"(lo), "v"(hi));
    return r;
}
__device__ __forceinline__ f16v zerov16() {
    f16v z;
    #pragma unroll
    for (int i = 0; i < 16; i++) z[i] = 0.f;
    return z;
}
// LDS-only barrier: lgkmcnt(0) drain + s_barrier. Keeps global (vmcnt) loads
// in flight across barriers; all intra-loop cross-wave traffic is LDS.
__device__ __forceinline__ void bar_lgkm() {
    asm volatile("s_waitcnt lgkmcnt(0)" ::: "memory");
    __builtin_amdgcn_s_barrier();
    __builtin_amdgcn_sched_barrier(0);
}
__device__ __forceinline__ void wait_lgkm() {
    asm volatile("s_waitcnt lgkmcnt(0)" ::: "memory");
}

union BF8U { unsigned u[4]; bf8 b; };

__global__ void wconv(const float* __restrict__ W1, const float* __restrict__ W2,
                      const float* __restrict__ W3, unsigned short* __restrict__ ws)
{
    int idx = blockIdx.x * 256 + threadIdx.x;
    if (idx >= WT_TOTAL) return;
    float v;
    if (idx < 5120) {
        int k5 = idx >> 10, rem = idx & 1023, fo = rem >> 4, fi = rem & 15;
        v = (fi < 3) ? W1[(k5 * 3 + fi) * HF + fo] : 0.f;
    } else if (idx < 25600) {
        int j = idx - 5120;
        int k5 = j >> 12, rem = j & 4095, fo = rem >> 6, fi = rem & 63;
        v = W2[(k5 * HF + fi) * HF + fo];
    } else {
        int j = idx - 25600;
        int k5 = j >> 12, rem = j & 4095, fo = rem >> 6, fi = rem & 63;
        v = W3[(k5 * HF + fi) * HF + fo];
    }
    ws[idx] = f2bf(v);
}

// R6 schedule (18 barrier windows, ping-pong parity, lgkm-only barriers, weight
// prefetch) with the SPILL removed via m-SPLIT: 512 threads = 8 waves, wave wg
// owns a single (np-tile mt = wg>>1, fo-half ht = wg&1). Per-wave persistent
// registers halve vs R6: af[7](14) + prev[8]+oldr[8](16) + acc(16) + bwp(16)
// = 62 (R6: 140 > 128 cap -> 6.25 MB scratch writes on the critical path).
// bfr/a fragments are streamed one-at-a-time inside the MFMA loops to keep
// temp live ranges short. No new dataflow: same windows, same parity scheme,
// same arithmetic order; TLP doubles (16 waves/CU).
__launch_bounds__(512, 4)
__global__ void chebreg(const float* __restrict__ x, const int* __restrict__ ei,
                        const float* __restrict__ lambda_max,
                        const unsigned short* __restrict__ Wt,
                        const float* __restrict__ b1, const float* __restrict__ b2,
                        const float* __restrict__ b3,
                        const float* __restrict__ bng, const float* __restrict__ bnb,
                        const float* __restrict__ bnm, const float* __restrict__ bnv,
                        const float* __restrict__ fc1w, const float* __restrict__ fc1b,
                        const float* __restrict__ fc2w, const float* __restrict__ fc2b,
                        float* __restrict__ out, int E_total, int epg)
{
    extern __shared__ char sm[];
    const int tid = threadIdx.x;
    const int g = blockIdx.x;
    const int ebase = g * epg, nbase = g * NPG;
    const int wg = tid >> 6, lane = tid & 63;
    const int l31 = lane & 31, hh = lane >> 5;
    const int ht  = wg & 1;          // f-tile: cols 32*ht..+31
    const int mt  = wg >> 1;         // n'-tile index 0..3
    const int fo  = ht * 32 + l31;

    unsigned* Cm   = (unsigned*)(sm + OFF_TC1);       // overlays Tc parity-1
    unsigned* deg  = (unsigned*)(sm + OFF_MISC);      // 112 u32
    float* pool    = (float*)(sm + OFF_MISC + 448);
    float* gvn     = (float*)(sm + OFF_MISC + 704);
    float* zf      = (float*)(sm + OFF_MISC + 960);
    float* logits  = (float*)(sm + OFF_MISC + 1088);
    float* lsep    = (float*)(sm + OFF_MISC + 1152);

    const float lam = lambda_max[g];
    const float two_l = 2.0f / lam;
    const float cl = two_l - 1.0f;

    // early x loads (consumed in W2; vmcnt rides across the W1 barrier)
    float xr0 = 0.f, xr1 = 0.f, xr2 = 0.f;
    const bool tv = (tid < NPG);
    if (tv) {
        xr0 = x[(nbase + tid) * 3 + 0];
        xr1 = x[(nbase + tid) * 3 + 1];
        xr2 = x[(nbase + tid) * 3 + 2];
    }

    // ---------------- W1: zero Tc0, Cm, Trm0, deg, pool ----------------
    for (int i = tid; i < SZ_TC / 16; i += 512)
        ((f4*)sm)[i] = (f4){0.f, 0.f, 0.f, 0.f};
    for (int i = tid; i < CMBYTES / 16; i += 512)
        ((f4*)(sm + OFF_TC1))[i] = (f4){0.f, 0.f, 0.f, 0.f};
    for (int i = tid; i < SZ_TRM / 16; i += 512)
        ((f4*)(sm + OFF_TRM0))[i] = (f4){0.f, 0.f, 0.f, 0.f};
    if (tid < 112) deg[tid] = 0u;
    if (tid < HF) pool[tid] = 0.f;
    bar_lgkm();

    // ---------------- W2: edge atomics (Cm + deg) + T0-init ----------------
    for (int e = tid; e < epg; e += 512) {
        int r = ei[ebase + e] - nbase;
        int c = ei[E_total + ebase + e] - nbase;
        atomicAdd(&Cm[r * CMW + (c >> 2)], 1u << (8 * (c & 3)));
        atomicAdd(&deg[r], 1u);
    }
    if (tv) {
        unsigned short h0 = f2bf(xr0);
        unsigned short h1 = f2bf(xr1);
        unsigned short h2 = f2bf(xr2);
        *(unsigned*)(sm + OFF_TRM0 + (tid * ST) * 2) = (unsigned)h0 | ((unsigned)h1 << 16);
        *(unsigned short*)(sm + OFF_TRM0 + (tid * ST + 2) * 2) = h2;
        *(unsigned short*)(sm + (0 * SAT + tid) * 2) = h0;
        *(unsigned short*)(sm + (1 * SAT + tid) * 2) = h1;
        *(unsigned short*)(sm + (2 * SAT + tid) * 2) = h2;
    }
    bar_lgkm();

    // ---------------- W3: A-hat fragments (single mt row-set per wave) ----------------
    bf8 af[7];
    {
        const int rr = 32 * mt + l31;
        const bool rv = (rr < NPG);
        unsigned dgr = rv ? deg[rr] : 0u;
        float disr = dgr ? rsqrtf((float)dgr) : 0.f;
        const float base = rv ? (-two_l * disr) : 0.f;
        #pragma unroll
        for (int Ks = 0; Ks < 7; Ks++) {
            int k0 = Ks * 16 + 8 * hh;
            unsigned w0 = rv ? Cm[rr * CMW + (k0 >> 2)]     : 0u;
            unsigned w1 = rv ? Cm[rr * CMW + (k0 >> 2) + 1] : 0u;
            float vv[8];
            #pragma unroll
            for (int j = 0; j < 8; j++) {
                int k = k0 + j;
                unsigned dg = deg[k];
                float dv = dg ? rsqrtf((float)dg) : 0.f;
                unsigned cnt = (((j < 4) ? w0 : w1) >> (8 * (k & 3))) & 255u;
                float v = base * (float)cnt * dv;
                if (rv && k == rr) v += cl;
                vv[j] = v;
            }
            BF8U t;
            #pragma unroll
            for (int p = 0; p < 4; p++) t.u[p] = cvt_pk_bf16(vv[2 * p], vv[2 * p + 1]);
            af[Ks] = t.b;
        }
    }
    // L0 k5=0 weight prefetch (consumed next window)
    bf8 bwp[4];
    bwp[0] = *(const bf8*)(Wt + fo * 16 + 8 * hh);
    bar_lgkm();   // Cm reads done before stage-1 writes clobber the Tc1 overlay

    // ---------------- 3 ChebConv layers ----------------
    f16v acc;
    unsigned prev[8], oldr[8];
    const float* bsv[3] = {b1, b2, b3};

    for (int L = 0; L < 3; L++) {
        const bool l1 = (L == 0);
        const unsigned short* Wl = l1 ? Wt : (Wt + (L == 1 ? 5120 : 25600));
        const int pb = L & 1;
        const int nKs = l1 ? 1 : 4;
        const float bias = bsv[L][fo];   // hoisted global load
        acc = zerov16();

        // prev = T0 at C-layout positions (L0 from Trm0; L>=1 already in regs)
        if (L == 0) {
            unsigned short tvv[16];
            #pragma unroll
            for (int r = 0; r < 16; r++) {
                int np = mt * 32 + (r & 3) + 8 * (r >> 2) + 4 * hh;
                tvv[r] = *(const unsigned short*)(sm + OFF_TRM0 + (np * ST + fo) * 2);
            }
            #pragma unroll
            for (int p = 0; p < 8; p++)
                prev[p] = (unsigned)tvv[2 * p] | ((unsigned)tvv[2 * p + 1] << 16);
        }

        for (int s = 1; s <= 4; s++) {
            const int rp = (pb + s - 1) & 1, wp = rp ^ 1;
            const char* tcR = sm + rp * SZ_TC;
            const char* trR = sm + OFF_TRM0 + rp * SZ_TRM;
            char* tcW = sm + wp * SZ_TC;
            char* trW = sm + OFF_TRM0 + wp * SZ_TRM;

            // TW(s-1) with prefetched weights (bwp holds k5=s-1); A streamed
            #pragma unroll
            for (int Ks = 0; Ks < 4; Ks++) {
                if (Ks < nKs) {
                    bf8 a = *(const bf8*)(trR +
                              ((mt * 32 + l31) * ST + Ks * 16 + 8 * hh) * 2);
                    acc = __builtin_amdgcn_mfma_f32_32x32x16_bf16(a, bwp[Ks], acc, 0, 0, 0);
                }
            }
            // prefetch k5=s (in flight across this window's barrier)
            if (l1) {
                bwp[0] = *(const bf8*)(Wl + (s * 64 + fo) * 16 + 8 * hh);
            } else {
                #pragma unroll
                for (int Ks = 0; Ks < 4; Ks++)
                    bwp[Ks] = *(const bf8*)(Wl + (s * 64 + fo) * 64 + Ks * 16 + 8 * hh);
            }

            // LHAT: B-frags streamed one-at-a-time (short live range)
            f16v c = zerov16();
            #pragma unroll
            for (int Ks = 0; Ks < 7; Ks++) {
                bf8 bb = *(const bf8*)(tcR + (fo * SAT + Ks * 16 + 8 * hh) * 2);
                c = __builtin_amdgcn_mfma_f32_32x32x16_bf16(af[Ks], bb, c, 0, 0, 0);
            }
            // Chebyshev recurrence + pack
            #pragma unroll
            for (int p = 0; p < 8; p++) {
                float ve = c[2 * p], vo = c[2 * p + 1];
                if (s >= 2) {
                    unsigned o = oldr[p];
                    ve = 2.f * ve - __uint_as_float(o << 16);
                    vo = 2.f * vo - __uint_as_float(o & 0xffff0000u);
                }
                oldr[p] = prev[p];
                prev[p] = cvt_pk_bf16(ve, vo);
            }
            // Tc[wp] writes (node-quads -> 4x b64); dead at s==4
            if (s < 4) {
                #pragma unroll
                for (int q4 = 0; q4 < 4; q4++) {
                    int np0 = mt * 32 + 8 * q4 + 4 * hh;
                    uint2 pk;
                    pk.x = prev[2 * q4];
                    pk.y = prev[2 * q4 + 1];
                    *(uint2*)(tcW + (fo * SAT + np0) * 2) = pk;
                }
            }
            // Trm[wp] writes: b16 lo + b16 hi per packed pair
            #pragma unroll
            for (int p = 0; p < 8; p++) {
                int r0 = 2 * p;
                int npb = mt * 32 + (r0 & 3) + 8 * (r0 >> 2) + 4 * hh;
                char* ad = trW + (npb * ST + fo) * 2;
                *(unsigned short*)ad = (unsigned short)prev[p];
                *(unsigned short*)(ad + ST * 2) = (unsigned short)(prev[p] >> 16);
            }
            bar_lgkm();   // single barrier: T_s visible + next-window WAR cover
        }

        // epi window: TW(4) reads Trm[pb] (T_4)
        {
            const char* trR = sm + OFF_TRM0 + pb * SZ_TRM;
            #pragma unroll
            for (int Ks = 0; Ks < 4; Ks++) {
                if (Ks < nKs) {
                    bf8 a = *(const bf8*)(trR +
                              ((mt * 32 + l31) * ST + Ks * 16 + 8 * hh) * 2);
                    acc = __builtin_amdgcn_mfma_f32_32x32x16_bf16(a, bwp[Ks], acc, 0, 0, 0);
                }
            }
        }

        if (L < 2) {
            // prefetch next layer's k5=0 (full 4-frag set)
            const unsigned short* Wn = Wt + (L == 0 ? 5120 : 25600);
            #pragma unroll
            for (int Ks = 0; Ks < 4; Ks++)
                bwp[Ks] = *(const bf8*)(Wn + fo * 64 + Ks * 16 + 8 * hh);

            const int op = pb ^ 1;
            char* tcW = sm + op * SZ_TC;
            char* trW = sm + OFF_TRM0 + op * SZ_TRM;
            #pragma unroll
            for (int p = 0; p < 8; p++) {
                float ve = fmaxf(acc[2 * p]     + bias, 0.f);
                float vo = fmaxf(acc[2 * p + 1] + bias, 0.f);
                prev[p] = cvt_pk_bf16(ve, vo);
            }
            #pragma unroll
            for (int q4 = 0; q4 < 4; q4++) {
                int np0 = mt * 32 + 8 * q4 + 4 * hh;
                uint2 pk;
                pk.x = prev[2 * q4];
                pk.y = prev[2 * q4 + 1];
                *(uint2*)(tcW + (fo * SAT + np0) * 2) = pk;
            }
            #pragma unroll
            for (int p = 0; p < 8; p++) {
                int r0 = 2 * p;
                int npb = mt * 32 + (r0 & 3) + 8 * (r0 >> 2) + 4 * hh;
                char* ad = trW + (npb * ST + fo) * 2;
                *(unsigned short*)ad = (unsigned short)prev[p];
                *(unsigned short*)(ad + ST * 2) = (unsigned short)(prev[p] >> 16);
            }
            bar_lgkm();   // T0' visible for next layer
        } else {
            float ssum = 0.f;
            #pragma unroll
            for (int r = 0; r < 16; r++) {
                int np = mt * 32 + (r & 3) + 8 * (r >> 2) + 4 * hh;
                float h = fmaxf(acc[r] + bias, 0.f);
                if (np < NPG) ssum += h;
            }
            ssum += __shfl_xor(ssum, 32, 64);
            if (hh == 0) atomicAdd(&pool[fo], ssum);
            bar_lgkm();   // final barrier: pool visible to wave 0
        }
    }

    // ---------------- tail: wave 0 solo, wave-synchronous (no barriers) ----------------
    if (wg == 0) {
        float gv = pool[lane] * (1.0f / NPG);
        gv = (gv - bnm[lane]) * rsqrtf(bnv[lane] + 1e-5f) * bng[lane] + bnb[lane];
        gvn[lane] = gv;
        wait_lgkm();
        if (lane < 32) {
            float a = fc1b[lane];
            for (int f = 0; f < HF; f++) a += gvn[f] * fc1w[f * 32 + lane];
            zf[lane] = fmaxf(a, 0.f);
        }
        wait_lgkm();
        if (lane < 10) {
            float a = fc2b[lane];
            for (int k = 0; k < 32; k++) a += zf[k] * fc2w[k * 10 + lane];
            logits[lane] = a;
        }
        wait_lgkm();
        if (lane == 0) {
            float m = logits[0];
            for (int i = 1; i < 10; i++) m = fmaxf(m, logits[i]);
            float s = 0.f;
            for (int i = 0; i < 10; i++) s += expf(logits[i] - m);
            lsep[0] = m + logf(s);
        }
        wait_lgkm();
        if (lane < 10) out[g * 10 + lane] = logits[lane] - lsep[0];
    }
}

extern "C" void kernel_launch(void* const* d_in, const int* in_sizes, int n_in,
                              void* d_out, int out_size, void* d_ws, size_t ws_size,
                              hipStream_t stream) {
    const float* x    = (const float*)d_in[0];
    const int*   ei   = (const int*)d_in[1];
    const float* lmax = (const float*)d_in[3];
    const float* W1   = (const float*)d_in[4];
    const float* b1   = (const float*)d_in[5];
    const float* W2   = (const float*)d_in[6];
    const float* b2   = (const float*)d_in[7];
    const float* W3   = (const float*)d_in[8];
    const float* b3   = (const float*)d_in[9];
    const float* bng  = (const float*)d_in[10];
    const float* bnb  = (const float*)d_in[11];
    const float* bnm  = (const float*)d_in[12];
    const float* bnv  = (const float*)d_in[13];
    const float* fc1w = (const float*)d_in[14];
    const float* fc1b = (const float*)d_in[15];
    const float* fc2w = (const float*)d_in[16];
    const float* fc2b = (const float*)d_in[17];

    const int E = in_sizes[1] / 2;
    const int G = in_sizes[3];
    const int epg = E / G;

    unsigned short* Wt = (unsigned short*)d_ws;

    wconv<<<(WT_TOTAL + 255) / 256, 256, 0, stream>>>(W1, W2, W3, Wt);

    hipFuncSetAttribute((const void*)chebreg,
                        hipFuncAttributeMaxDynamicSharedMemorySize, SMEM_BYTES);

    chebreg<<<G, 512, SMEM_BYTES, stream>>>(x, ei, lmax, Wt, b1, b2, b3,
                                            bng, bnb, bnm, bnv, fc1w, fc1b, fc2w, fc2b,
                                            (float*)d_out, E, epg);
}